// Round 4
// baseline (318.987 us; speedup 1.0000x reference)
//
#include <hip/hip_runtime.h>

typedef _Float16 half8 __attribute__((ext_vector_type(8)));
typedef _Float16 half4 __attribute__((ext_vector_type(4)));
typedef float floatx16 __attribute__((ext_vector_type(16)));

constexpr int Bn = 32768, Kn = 4096, Dn = 256;
constexpr int BM = 128;          // rows per block
constexpr int BNS = 64;          // codes per ni step
constexpr int NI = Kn / BNS;     // 64
constexpr int NCH = NI * 4;      // 256 chunks; chunk = 64 codes x 64 k x {hi|lo} = 16KB

// ---- prep: exact fp32 ||e||^2 + swizzle-baked f16 hi|lo codebook ----
// w16 layout: [code][kc 0..3][256B row: hi 128B | lo 128B], each 256B row's 16B
// granules XOR-permuted by (code&15) so main-kernel DMA is a linear row copy.
__global__ void prep_kernel(const float* __restrict__ w, float* __restrict__ esq,
                            char* __restrict__ w16) {
    int code = blockIdx.x * 4 + (threadIdx.x >> 6);
    int l = threadIdx.x & 63;
    float4 v = *reinterpret_cast<const float4*>(w + (size_t)code * Dn + l * 4);
    float s = v.x * v.x + v.y * v.y + v.z * v.z + v.w * v.w;
    #pragma unroll
    for (int off = 32; off; off >>= 1) s += __shfl_xor(s, off);
    if (l == 0) esq[code] = s;

    float fv[4] = {v.x, v.y, v.z, v.w};
    half4 h, lo;
    #pragma unroll
    for (int j = 0; j < 4; ++j) {
        _Float16 hh = (_Float16)fv[j];
        h[j] = hh;
        lo[j] = (_Float16)(fv[j] - (float)hh);
    }
    const int kc = l >> 4;               // k = l*4 -> 64-k segment
    const int o_h = (l & 15) * 8;        // byte offset in hi region
    const int swz = (code & 15) << 4;
    char* row = w16 + (size_t)code * 1024 + kc * 256;
    *reinterpret_cast<half4*>(row + (o_h ^ swz)) = h;
    *reinterpret_cast<half4*>(row + ((o_h + 128) ^ swz)) = lo;
}

#define GLDS(gsrc, ldsoff)                                                        \
    __builtin_amdgcn_global_load_lds(                                             \
        (const __attribute__((address_space(1))) unsigned int*)(const void*)(gsrc),\
        (__attribute__((address_space(3))) unsigned int*)(void*)(smem + (ldsoff)), \
        16, 0, 0)

#define MFMA(a, b, c) __builtin_amdgcn_mfma_f32_32x32x16_f16((a), (b), (c), 0, 0, 0)

// LDS map: bufs 4x16384 [0,65536) | esq_s [65536,81920) | comb [81920,83968) | idxF [83968,84480)
__launch_bounds__(256, 1)
__global__ void vq_kernel(const float* __restrict__ z, const float* __restrict__ w,
                          const float* __restrict__ esq, const char* __restrict__ w16,
                          float* __restrict__ out0, float* __restrict__ out1,
                          float* __restrict__ out2) {
    __shared__ char smem[84480];
    const int tid = threadIdx.x;
    const int wv = tid >> 6, l = tid & 63;
    const int mw = wv >> 1, nw = wv & 1;       // 2 M-waves x 2 N-waves
    const int lh = l >> 5, ll = l & 31;
    const int blkRow = blockIdx.x * BM;

    // esq -> LDS
    float* esq_s = reinterpret_cast<float*>(smem + 65536);
    #pragma unroll
    for (int j = 0; j < 16; ++j) esq_s[j * 256 + tid] = esq[j * 256 + tid];

    // A: 64 rows per wave (2 Msets of 32), f16 hi/lo in regs (256 VGPR).
    // lane: row=ll, k = ks*16 + lh*8 + j
    half8 a_hi[2][16], a_lo[2][16];
    #pragma unroll
    for (int t = 0; t < 2; ++t) {
        const float* zr = z + (size_t)(blkRow + mw * 64 + t * 32 + ll) * Dn + lh * 8;
        #pragma unroll
        for (int ks = 0; ks < 16; ++ks) {
            float4 f0 = *reinterpret_cast<const float4*>(zr + ks * 16);
            float4 f1 = *reinterpret_cast<const float4*>(zr + ks * 16 + 4);
            float fv[8] = {f0.x, f0.y, f0.z, f0.w, f1.x, f1.y, f1.z, f1.w};
            #pragma unroll
            for (int j = 0; j < 8; ++j) {
                _Float16 h = (_Float16)fv[j];
                a_hi[t][ks][j] = h;
                a_lo[t][ks][j] = (_Float16)(fv[j] - (float)h);
            }
        }
    }

    // DMA: each wave stages 4KB of the 16KB chunk as 4 linear 1KB row-copies.
    // lane-static source offset within chunk: granule G = wv*256 + j*64 + l
    const int G0 = wv * 256 + l;
    const size_t srcOff0 = (size_t)(G0 >> 4) * 1024 + (G0 & 15) * 16;

    // ds_read addresses (swizzled): col c = nw*32+ll
    int addrH[4], addrL[4];
    {
        const int c_loc = nw * 32 + ll;
        const int swz = (c_loc & 15) << 4;
        #pragma unroll
        for (int ks = 0; ks < 4; ++ks) {
            const int o = ks * 32 + lh * 16;
            addrH[ks] = c_loc * 256 + (o ^ swz);
            addrL[ks] = c_loc * 256 + ((o + 128) ^ swz);
        }
    }

    float rbv0[16], rbv1[16];
    int rbi0[16], rbi1[16];
    #pragma unroll
    for (int q = 0; q < 16; ++q) { rbv0[q] = 3.4e38f; rbv1[q] = 3.4e38f; rbi0[q] = 0; rbi1[q] = 0; }

    asm volatile("s_waitcnt vmcnt(0)" ::: "memory");
    __syncthreads();   // esq staged, prologue clean

    // prologue: chunks 0,1 -> bufs 0,1
    {
        const char* s0 = w16 + srcOff0;
        const char* s1 = w16 + 256 + srcOff0;
        const int d0 = wv * 4096, d1 = 16384 + wv * 4096;
        GLDS(s0, d0); GLDS(s0 + 4096, d0 + 1024); GLDS(s0 + 8192, d0 + 2048); GLDS(s0 + 12288, d0 + 3072);
        GLDS(s1, d1); GLDS(s1 + 4096, d1 + 1024); GLDS(s1 + 8192, d1 + 2048); GLDS(s1 + 12288, d1 + 3072);
    }

    for (int ni = 0; ni < NI; ++ni) {
        floatx16 acc0 = {}, acc1 = {};
        #pragma unroll
        for (int kc = 0; kc < 4; ++kc) {
            const int c = ni * 4 + kc;
            if (c + 2 < NCH) {   // prefetch chunk c+2 into buf (kc+2)&3 (reads ended 2 barriers ago)
                const char* s2 = w16 + (size_t)((c + 2) >> 2) * 65536 + ((c + 2) & 3) * 256 + srcOff0;
                const int d2 = (((kc + 2) & 3) * 16384) + wv * 4096;
                GLDS(s2, d2); GLDS(s2 + 4096, d2 + 1024);
                GLDS(s2 + 8192, d2 + 2048); GLDS(s2 + 12288, d2 + 3072);
                asm volatile("s_waitcnt vmcnt(8)" ::: "memory");
            } else if (c + 1 < NCH) {
                asm volatile("s_waitcnt vmcnt(4)" ::: "memory");
            } else {
                asm volatile("s_waitcnt vmcnt(0)" ::: "memory");
            }
            __builtin_amdgcn_s_barrier();
            asm volatile("" ::: "memory");
            const char* base = smem + kc * 16384;
            __builtin_amdgcn_s_setprio(1);
            #pragma unroll
            for (int ks = 0; ks < 4; ++ks) {
                const half8 bh = *reinterpret_cast<const half8*>(base + addrH[ks]);
                const half8 bl = *reinterpret_cast<const half8*>(base + addrL[ks]);
                const int ksg = kc * 4 + ks;
                // fp16x3 emulated-fp32 cross, two independent acc chains (dep dist 64cy)
                acc0 = MFMA(a_hi[0][ksg], bh, acc0);
                acc1 = MFMA(a_hi[1][ksg], bh, acc1);
                acc0 = MFMA(a_hi[0][ksg], bl, acc0);
                acc1 = MFMA(a_hi[1][ksg], bl, acc1);
                acc0 = MFMA(a_lo[0][ksg], bh, acc0);
                acc1 = MFMA(a_lo[1][ksg], bh, acc1);
            }
            __builtin_amdgcn_s_setprio(0);
        }
        // argmin update; lane col = ni*64 + nw*32 + ll (ascending ni: strict < = first occurrence)
        const float e = esq_s[ni * 64 + nw * 32 + ll];
        const int col = ni * 64 + nw * 32 + ll;
        #pragma unroll
        for (int q = 0; q < 16; ++q) {
            const float v0 = fmaf(-2.f, acc0[q], e);
            if (v0 < rbv0[q]) { rbv0[q] = v0; rbi0[q] = col; }
            const float v1 = fmaf(-2.f, acc1[q], e);
            if (v1 < rbv1[q]) { rbv1[q] = v1; rbi1[q] = col; }
        }
    }

    // cross-lane argmin over 32 cols (shfl_xor < 32 stays within each half)
    #pragma unroll
    for (int off = 1; off < 32; off <<= 1) {
        #pragma unroll
        for (int q = 0; q < 16; ++q) {
            float ov0 = __shfl_xor(rbv0[q], off); int oi0 = __shfl_xor(rbi0[q], off);
            if (ov0 < rbv0[q] || (ov0 == rbv0[q] && oi0 < rbi0[q])) { rbv0[q] = ov0; rbi0[q] = oi0; }
            float ov1 = __shfl_xor(rbv1[q], off); int oi1 = __shfl_xor(rbi1[q], off);
            if (ov1 < rbv1[q] || (ov1 == rbv1[q] && oi1 < rbi1[q])) { rbv1[q] = ov1; rbi1[q] = oi1; }
        }
    }

    __syncthreads();
    int2* comb = reinterpret_cast<int2*>(smem + 81920);   // [128 rows][2 nw]
    if (ll == 0) {
        #pragma unroll
        for (int q = 0; q < 16; ++q) {   // m74 C-layout: row = (q&3) + 8*(q>>2) + 4*lh
            const int r32 = (q & 3) + 8 * (q >> 2) + 4 * lh;
            comb[(mw * 64 + r32) * 2 + nw] = make_int2(__float_as_int(rbv0[q]), rbi0[q]);
            comb[(mw * 64 + 32 + r32) * 2 + nw] = make_int2(__float_as_int(rbv1[q]), rbi1[q]);
        }
    }
    __syncthreads();
    int* idxF = reinterpret_cast<int*>(smem + 83968);
    if (tid < 128) {
        int2 c0 = comb[tid * 2], c1 = comb[tid * 2 + 1];
        float v0 = __int_as_float(c0.x), v1 = __int_as_float(c1.x);
        idxF[tid] = (v1 < v0 || (v1 == v0 && c1.y < c0.y)) ? c1.y : c0.y;
    }
    __syncthreads();

    // gather: out0 = z + (q - z) (ref's exact fp32 expr), out1 = q, out2 = idx
    {
        const int r = tid >> 1, p2 = tid & 1;
        const int gRow = blkRow + r;
        const int idx = idxF[r];
        const float* wr = w + (size_t)idx * Dn + p2 * 128;
        const float* zr = z + (size_t)gRow * Dn + p2 * 128;
        float* o0 = out0 + (size_t)gRow * Dn + p2 * 128;
        float* o1 = out1 + (size_t)gRow * Dn + p2 * 128;
        #pragma unroll
        for (int q = 0; q < 32; ++q) {
            float4 wq = *reinterpret_cast<const float4*>(wr + q * 4);
            float4 zq = *reinterpret_cast<const float4*>(zr + q * 4);
            *reinterpret_cast<float4*>(o1 + q * 4) = wq;
            float4 sg;
            sg.x = zq.x + (wq.x - zq.x);
            sg.y = zq.y + (wq.y - zq.y);
            sg.z = zq.z + (wq.z - zq.z);
            sg.w = zq.w + (wq.w - zq.w);
            *reinterpret_cast<float4*>(o0 + q * 4) = sg;
        }
        if (p2 == 0) out2[gRow] = (float)idx;
    }
}

extern "C" void kernel_launch(void* const* d_in, const int* in_sizes, int n_in,
                              void* d_out, int out_size, void* d_ws, size_t ws_size,
                              hipStream_t stream) {
    (void)in_sizes; (void)n_in; (void)out_size; (void)ws_size;
    const float* z = (const float*)d_in[0];
    const float* w = (const float*)d_in[1];
    float* esq = (float*)d_ws;                        // 16 KB
    char* w16 = (char*)d_ws + 16384;                  // 4 MB swizzle-baked hi|lo codebook
    float* out0 = (float*)d_out;
    float* out1 = out0 + (size_t)Bn * Dn;
    float* out2 = out1 + (size_t)Bn * Dn;

    prep_kernel<<<Kn / 4, 256, 0, stream>>>(w, esq, w16);
    vq_kernel<<<Bn / BM, 256, 0, stream>>>(z, w, esq, w16, out0, out1, out2);
}

// Round 5
// 318.659 us; speedup vs baseline: 1.0010x; 1.0010x over previous
//
#include <hip/hip_runtime.h>

typedef _Float16 half8 __attribute__((ext_vector_type(8)));
typedef _Float16 half4 __attribute__((ext_vector_type(4)));
typedef float floatx16 __attribute__((ext_vector_type(16)));

constexpr int Bn = 32768, Kn = 4096, Dn = 256;
constexpr int BM = 128;          // rows per block
constexpr int NI = 64;           // ni steps (64 codes each)
constexpr int NCH = 256;         // chunks; chunk = 64 codes x 64 k x {hi|lo} = 16KB

// ---- prep: exact fp32 ||e||^2 + swizzle-baked f16 hi|lo codebook ----
// w16 layout: [code][kc 0..3][256B row: hi 128B | lo 128B]; each row's 16B
// granules XOR-permuted by (code&15) so main-kernel DMA is a linear row copy.
__global__ void prep_kernel(const float* __restrict__ w, float* __restrict__ esq,
                            char* __restrict__ w16) {
    int code = blockIdx.x * 4 + (threadIdx.x >> 6);
    int l = threadIdx.x & 63;
    float4 v = *reinterpret_cast<const float4*>(w + (size_t)code * Dn + l * 4);
    float s = v.x * v.x + v.y * v.y + v.z * v.z + v.w * v.w;
    #pragma unroll
    for (int off = 32; off; off >>= 1) s += __shfl_xor(s, off);
    if (l == 0) esq[code] = s;

    float fv[4] = {v.x, v.y, v.z, v.w};
    half4 h, lo;
    #pragma unroll
    for (int j = 0; j < 4; ++j) {
        _Float16 hh = (_Float16)fv[j];
        h[j] = hh;
        lo[j] = (_Float16)(fv[j] - (float)hh);
    }
    const int kc = l >> 4;
    const int o_h = (l & 15) * 8;
    const int swz = (code & 15) << 4;
    char* row = w16 + (size_t)code * 1024 + kc * 256;
    *reinterpret_cast<half4*>(row + (o_h ^ swz)) = h;
    *reinterpret_cast<half4*>(row + ((o_h + 128) ^ swz)) = lo;
}

#define GLDS(gsrc, ldsoff)                                                        \
    __builtin_amdgcn_global_load_lds(                                             \
        (const __attribute__((address_space(1))) unsigned int*)(const void*)(gsrc),\
        (__attribute__((address_space(3))) unsigned int*)(void*)(smem + (ldsoff)), \
        16, 0, 0)

#define MFMA(a, b, c) __builtin_amdgcn_mfma_f32_32x32x16_f16((a), (b), (c), 0, 0, 0)

// LDS map: bufs 4x16384 [0,65536) | esq_s [65536,81920) | comb [81920,83968) | idxF [83968,84480)
__global__ void
__launch_bounds__(256, 1)
__attribute__((amdgpu_waves_per_eu(1, 1)))
vq_kernel(const float* __restrict__ z, const float* __restrict__ w,
          const float* __restrict__ esq, const char* __restrict__ w16,
          float* __restrict__ out0, float* __restrict__ out1,
          float* __restrict__ out2) {
    __shared__ char smem[84480];
    const int tid = threadIdx.x;
    const int wv = tid >> 6, l = tid & 63;
    const int mw = wv >> 1, nw = wv & 1;       // 2 M-groups (64 rows) x 2 N-halves (32 cols)
    const int lh = l >> 5, ll = l & 31;
    const int blkRow = blockIdx.x * BM;

    // esq -> LDS (before the syncthreads that opens the counted-vmcnt regime)
    float* esq_s = reinterpret_cast<float*>(smem + 65536);
    #pragma unroll
    for (int j = 0; j < 16; ++j) esq_s[j * 256 + tid] = esq[j * 256 + tid];

    // A: 64 z-rows per wave (2 Msets of 32) as f16 hi/lo, flat static arrays (256 VGPR).
    // lane: row = ll (within Mset), k = ks*16 + lh*8 + j
    half8 a_hi[32], a_lo[32];
    #pragma unroll
    for (int t = 0; t < 2; ++t) {
        const float* zr = z + (size_t)(blkRow + mw * 64 + t * 32 + ll) * Dn + lh * 8;
        #pragma unroll
        for (int ks = 0; ks < 16; ++ks) {
            float4 f0 = *reinterpret_cast<const float4*>(zr + ks * 16);
            float4 f1 = *reinterpret_cast<const float4*>(zr + ks * 16 + 4);
            float fv[8] = {f0.x, f0.y, f0.z, f0.w, f1.x, f1.y, f1.z, f1.w};
            #pragma unroll
            for (int j = 0; j < 8; ++j) {
                _Float16 h = (_Float16)fv[j];
                a_hi[t * 16 + ks][j] = h;
                a_lo[t * 16 + ks][j] = (_Float16)(fv[j] - (float)h);
            }
        }
    }

    // DMA: wave stages 4KB/chunk as 4 linear 1KB row-copies (granule G = wv*256 + j*64 + l)
    const int G0 = wv * 256 + l;
    const size_t srcOff0 = (size_t)(G0 >> 4) * 1024 + (G0 & 15) * 16;

    // ds_read addrs (swizzled), col c = nw*32 + ll
    int addrH[4], addrL[4];
    {
        const int c_loc = nw * 32 + ll;
        const int swz = (c_loc & 15) << 4;
        #pragma unroll
        for (int ks = 0; ks < 4; ++ks) {
            const int o = ks * 32 + lh * 16;
            addrH[ks] = c_loc * 256 + (o ^ swz);
            addrL[ks] = c_loc * 256 + ((o + 128) ^ swz);
        }
    }

    float rbv0[16], rbv1[16];
    unsigned rbn0[4] = {0, 0, 0, 0}, rbn1[4] = {0, 0, 0, 0};   // packed winning-ni bytes
    #pragma unroll
    for (int q = 0; q < 16; ++q) { rbv0[q] = 3.4e38f; rbv1[q] = 3.4e38f; }

    asm volatile("s_waitcnt vmcnt(0)" ::: "memory");
    __syncthreads();   // esq + A loads drained; vmcnt counter at 0

    // prologue: DMA chunks 0,1
    {
        const char* s0 = w16 + srcOff0;
        const char* s1 = w16 + 256 + srcOff0;
        const int d0 = wv * 4096, d1 = 16384 + wv * 4096;
        GLDS(s0, d0); GLDS(s0 + 4096, d0 + 1024); GLDS(s0 + 8192, d0 + 2048); GLDS(s0 + 12288, d0 + 3072);
        GLDS(s1, d1); GLDS(s1 + 4096, d1 + 1024); GLDS(s1 + 8192, d1 + 2048); GLDS(s1 + 12288, d1 + 3072);
    }
    asm volatile("s_waitcnt vmcnt(4)" ::: "memory");   // chunk 0 complete
    __builtin_amdgcn_s_barrier();
    asm volatile("" ::: "memory");

    // frag double-buffer: set parity = chunk&1 (half8 x 16 = 64 VGPR)
    half8 sh0[4], sl0[4], sh1[4], sl1[4];
    #pragma unroll
    for (int ks = 0; ks < 4; ++ks) {   // frags of chunk 0 -> set0
        sh0[ks] = *reinterpret_cast<const half8*>(smem + addrH[ks]);
        sl0[ks] = *reinterpret_cast<const half8*>(smem + addrL[ks]);
    }

    for (int ni = 0; ni < NI; ++ni) {
        floatx16 acc0 = {}, acc1 = {};
        #pragma unroll
        for (int kc = 0; kc < 4; ++kc) {
            const int c = ni * 4 + kc;
            if (c + 2 < NCH) {   // prefetch chunk c+2 -> buf (kc+2)&3
                const char* s2 = w16 + (size_t)((c + 2) >> 2) * 65536 + ((c + 2) & 3) * 256 + srcOff0;
                const int d2 = (((kc + 2) & 3) * 16384) + wv * 4096;
                GLDS(s2, d2); GLDS(s2 + 4096, d2 + 1024);
                GLDS(s2 + 8192, d2 + 2048); GLDS(s2 + 12288, d2 + 3072);
                asm volatile("s_waitcnt vmcnt(4)" ::: "memory");   // c and c+1 complete
            } else {
                asm volatile("s_waitcnt vmcnt(0)" ::: "memory");
            }
            __builtin_amdgcn_s_barrier();
            asm volatile("" ::: "memory");
            // read-ahead: frags of chunk c+1 (buf (kc+1)&3) into the other set,
            // overlapping the MFMA cluster on chunk c's frags (read last phase).
            const char* nb = smem + ((kc + 1) & 3) * 16384;
            if (kc & 1) {   // current set1, next -> set0
                if (c + 1 < NCH) {
                    #pragma unroll
                    for (int ks = 0; ks < 4; ++ks) {
                        sh0[ks] = *reinterpret_cast<const half8*>(nb + addrH[ks]);
                        sl0[ks] = *reinterpret_cast<const half8*>(nb + addrL[ks]);
                    }
                }
                __builtin_amdgcn_s_setprio(1);
                #pragma unroll
                for (int ks = 0; ks < 4; ++ks) {
                    const int ksg = kc * 4 + ks;
                    acc0 = MFMA(a_hi[ksg], sh1[ks], acc0);
                    acc1 = MFMA(a_hi[16 + ksg], sh1[ks], acc1);
                    acc0 = MFMA(a_hi[ksg], sl1[ks], acc0);
                    acc1 = MFMA(a_hi[16 + ksg], sl1[ks], acc1);
                    acc0 = MFMA(a_lo[ksg], sh1[ks], acc0);
                    acc1 = MFMA(a_lo[16 + ksg], sh1[ks], acc1);
                }
                __builtin_amdgcn_s_setprio(0);
            } else {        // current set0, next -> set1
                if (c + 1 < NCH) {
                    #pragma unroll
                    for (int ks = 0; ks < 4; ++ks) {
                        sh1[ks] = *reinterpret_cast<const half8*>(nb + addrH[ks]);
                        sl1[ks] = *reinterpret_cast<const half8*>(nb + addrL[ks]);
                    }
                }
                __builtin_amdgcn_s_setprio(1);
                #pragma unroll
                for (int ks = 0; ks < 4; ++ks) {
                    const int ksg = kc * 4 + ks;
                    acc0 = MFMA(a_hi[ksg], sh0[ks], acc0);
                    acc1 = MFMA(a_hi[16 + ksg], sh0[ks], acc1);
                    acc0 = MFMA(a_hi[ksg], sl0[ks], acc0);
                    acc1 = MFMA(a_hi[16 + ksg], sl0[ks], acc1);
                    acc0 = MFMA(a_lo[ksg], sh0[ks], acc0);
                    acc1 = MFMA(a_lo[16 + ksg], sh0[ks], acc1);
                }
                __builtin_amdgcn_s_setprio(0);
            }
        }
        // argmin update: lane col = ni*64 + nw*32 + ll; ascending ni + strict < = first occurrence
        const float e = esq_s[ni * 64 + nw * 32 + ll];
        #pragma unroll
        for (int q = 0; q < 16; ++q) {
            const int sh = (q & 3) * 8;
            const unsigned msk = ~(255u << sh);
            const float v0 = fmaf(-2.f, acc0[q], e);
            if (v0 < rbv0[q]) { rbv0[q] = v0; rbn0[q >> 2] = (rbn0[q >> 2] & msk) | ((unsigned)ni << sh); }
            const float v1 = fmaf(-2.f, acc1[q], e);
            if (v1 < rbv1[q]) { rbv1[q] = v1; rbn1[q >> 2] = (rbn1[q >> 2] & msk) | ((unsigned)ni << sh); }
        }
    }

    // final per-row argmin: unpack ni -> col, lexicographic shfl reduce over 32 lanes
    __syncthreads();
    int2* comb = reinterpret_cast<int2*>(smem + 81920);   // [128 rows][2 nw]
    #pragma unroll
    for (int q = 0; q < 16; ++q) {
        float v0 = rbv0[q], v1 = rbv1[q];
        int i0 = (int)((rbn0[q >> 2] >> ((q & 3) * 8)) & 255u) * 64 + nw * 32 + ll;
        int i1 = (int)((rbn1[q >> 2] >> ((q & 3) * 8)) & 255u) * 64 + nw * 32 + ll;
        #pragma unroll
        for (int off = 1; off < 32; off <<= 1) {
            float ov0 = __shfl_xor(v0, off); int oi0 = __shfl_xor(i0, off);
            if (ov0 < v0 || (ov0 == v0 && oi0 < i0)) { v0 = ov0; i0 = oi0; }
            float ov1 = __shfl_xor(v1, off); int oi1 = __shfl_xor(i1, off);
            if (ov1 < v1 || (ov1 == v1 && oi1 < i1)) { v1 = ov1; i1 = oi1; }
        }
        if (ll == 0) {   // m74 C-layout: row = (q&3) + 8*(q>>2) + 4*lh
            const int r32 = (q & 3) + 8 * (q >> 2) + 4 * lh;
            comb[(mw * 64 + r32) * 2 + nw] = make_int2(__float_as_int(v0), i0);
            comb[(mw * 64 + 32 + r32) * 2 + nw] = make_int2(__float_as_int(v1), i1);
        }
    }
    __syncthreads();
    int* idxF = reinterpret_cast<int*>(smem + 83968);
    if (tid < 128) {
        int2 c0 = comb[tid * 2], c1 = comb[tid * 2 + 1];
        float v0 = __int_as_float(c0.x), v1 = __int_as_float(c1.x);
        idxF[tid] = (v1 < v0 || (v1 == v0 && c1.y < c0.y)) ? c1.y : c0.y;
    }
    __syncthreads();

    // gather: out0 = z + (q - z) (ref's exact fp32 expr), out1 = q, out2 = idx
    {
        const int r = tid >> 1, p2 = tid & 1;
        const int gRow = blkRow + r;
        const int idx = idxF[r];
        const float* wr = w + (size_t)idx * Dn + p2 * 128;
        const float* zr = z + (size_t)gRow * Dn + p2 * 128;
        float* o0 = out0 + (size_t)gRow * Dn + p2 * 128;
        float* o1 = out1 + (size_t)gRow * Dn + p2 * 128;
        #pragma unroll
        for (int q = 0; q < 32; ++q) {
            float4 wq = *reinterpret_cast<const float4*>(wr + q * 4);
            float4 zq = *reinterpret_cast<const float4*>(zr + q * 4);
            *reinterpret_cast<float4*>(o1 + q * 4) = wq;
            float4 sg;
            sg.x = zq.x + (wq.x - zq.x);
            sg.y = zq.y + (wq.y - zq.y);
            sg.z = zq.z + (wq.z - zq.z);
            sg.w = zq.w + (wq.w - zq.w);
            *reinterpret_cast<float4*>(o0 + q * 4) = sg;
        }
        if (p2 == 0) out2[gRow] = (float)idx;
    }
}

extern "C" void kernel_launch(void* const* d_in, const int* in_sizes, int n_in,
                              void* d_out, int out_size, void* d_ws, size_t ws_size,
                              hipStream_t stream) {
    (void)in_sizes; (void)n_in; (void)out_size; (void)ws_size;
    const float* z = (const float*)d_in[0];
    const float* w = (const float*)d_in[1];
    float* esq = (float*)d_ws;                        // 16 KB
    char* w16 = (char*)d_ws + 16384;                  // 4 MB swizzle-baked hi|lo codebook
    float* out0 = (float*)d_out;
    float* out1 = out0 + (size_t)Bn * Dn;
    float* out2 = out1 + (size_t)Bn * Dn;

    prep_kernel<<<Kn / 4, 256, 0, stream>>>(w, esq, w16);
    vq_kernel<<<Bn / BM, 256, 0, stream>>>(z, w, esq, w16, out0, out1, out2);
}